// Round 9
// baseline (130.099 us; speedup 1.0000x reference)
//
#include <hip/hip_runtime.h>

#define DIM 256
#define NHEADS 8
#define HDIM 32

typedef _Float16 half8_t __attribute__((ext_vector_type(8)));
typedef _Float16 half4_t __attribute__((ext_vector_type(4)));
typedef float float4_t __attribute__((ext_vector_type(4)));

__device__ __forceinline__ float fast_exp2(float x) {
#if __has_builtin(__builtin_amdgcn_exp2f)
    return __builtin_amdgcn_exp2f(x);
#else
    return __expf(x * 0.6931471805599453f);
#endif
}

__device__ __forceinline__ void gload_lds16(const void* g, void* l) {
    __builtin_amdgcn_global_load_lds((const __attribute__((address_space(1))) void*)g,
                                     (__attribute__((address_space(3))) void*)l,
                                     16, 0, 0);
}

// ---------------------------------------------------------------------------
// prep: (a) x fp32 -> fp16 flat; (b) Wqkv [256,768] -> WqT [768,256] fp16;
//       (c) Wout [256,256] -> WoT [256,256] fp16 (transposed for B-frags).
// ---------------------------------------------------------------------------
__global__ __launch_bounds__(256) void prep(const float* __restrict__ x,
                                            const float* __restrict__ Wqkv,
                                            const float* __restrict__ Wout,
                                            _Float16* __restrict__ xh,
                                            _Float16* __restrict__ WqT,
                                            _Float16* __restrict__ WoT) {
    __shared__ float ts[32][33];
    const int bid = blockIdx.x, t = threadIdx.x;
    if (bid < 1024) {
        size_t idx = (size_t)bid * 2048 + (size_t)t * 8;
        float tmp[8];
        *reinterpret_cast<float4*>(tmp)     = *reinterpret_cast<const float4*>(x + idx);
        *reinterpret_cast<float4*>(tmp + 4) = *reinterpret_cast<const float4*>(x + idx + 4);
        half8_t h;
        #pragma unroll
        for (int j = 0; j < 8; ++j) h[j] = (_Float16)tmp[j];
        *reinterpret_cast<half8_t*>(xh + idx) = h;
    } else {
        const float* src; _Float16* dst; int K, N, kb, nb;
        if (bid < 1024 + 192) { int b2 = bid - 1024; src = Wqkv; dst = WqT; K = 256; N = 768; nb = b2 % 24; kb = b2 / 24; }
        else                  { int b3 = bid - 1216; src = Wout; dst = WoT; K = 256; N = 256; nb = b3 % 8;  kb = b3 / 8; }
        const int tx = t & 31, ty = t >> 5;
        #pragma unroll
        for (int i = 0; i < 4; ++i) {
            int k = kb * 32 + ty + i * 8;
            ts[ty + i * 8][tx] = src[(size_t)k * N + nb * 32 + tx];
        }
        __syncthreads();
        #pragma unroll
        for (int i = 0; i < 4; ++i) {
            int nl = ty + i * 8;
            dst[(size_t)(nb * 32 + nl) * K + kb * 32 + tx] = (_Float16)ts[tx][nl];
        }
    }
}

// ---------------------------------------------------------------------------
// fp16 MFMA GEMM (qkv): C[M,N] = A[M,K] @ BT[N,K]^T, LDS-staged.
// 64x128 tile, BK=32, 4 waves. Tiles with n0>=512 are V -> written TRANSPOSED
// to VT[b][h][hd][token]; Q columns (n0<256) pre-scaled by scale*log2(e).
// ---------------------------------------------------------------------------
__global__ __launch_bounds__(256) void gemm_qkv(const _Float16* __restrict__ A,
                                                const _Float16* __restrict__ BT,
                                                _Float16* __restrict__ Cv,
                                                _Float16* __restrict__ VTo) {
    constexpr int K = 256, ldc = 512;
    __shared__ alignas(16) _Float16 As[64 * 32];
    __shared__ alignas(16) _Float16 Bs[128 * 32];
    const int t = threadIdx.x, lane = t & 63, wave = t >> 6;
    const int l16 = lane & 15, quad = lane >> 4;
    const int m0 = blockIdx.y * 64, n0 = blockIdx.x * 128;
    const int wr = (wave >> 1) * 32, wc = (wave & 1) * 64;
    constexpr float QS = 0.17677669529663687f * 1.4426950408889634f;  // scale*log2e
    float4_t acc[2][4];
    #pragma unroll
    for (int i = 0; i < 2; ++i)
        #pragma unroll
        for (int j = 0; j < 4; ++j) acc[i][j] = (float4_t){0.f, 0.f, 0.f, 0.f};

    const int srow = lane >> 2;
    const int scol = (lane & 3) * 8;

    for (int k0 = 0; k0 < K; k0 += 32) {
        {
            int chunk = wave;                       // 4 chunks of 16 rows = 64
            int r = chunk * 16 + srow;
            gload_lds16(A + (size_t)(m0 + r) * K + k0 + scol, As + chunk * 512);
        }
        #pragma unroll
        for (int i = 0; i < 2; ++i) {
            int chunk = i * 4 + wave;
            int r = chunk * 16 + srow;
            gload_lds16(BT + (size_t)(n0 + r) * K + k0 + scol, Bs + chunk * 512);
        }
        __syncthreads();
        half8_t af[2], bf[4];
        #pragma unroll
        for (int i = 0; i < 2; ++i)
            af[i] = *reinterpret_cast<const half8_t*>(As + (wr + i * 16 + l16) * 32 + quad * 8);
        #pragma unroll
        for (int j = 0; j < 4; ++j)
            bf[j] = *reinterpret_cast<const half8_t*>(Bs + (wc + j * 16 + l16) * 32 + quad * 8);
        #pragma unroll
        for (int i = 0; i < 2; ++i)
            #pragma unroll
            for (int j = 0; j < 4; ++j)
                acc[i][j] = __builtin_amdgcn_mfma_f32_16x16x32_f16(af[i], bf[j], acc[i][j], 0, 0, 0);
        __syncthreads();
    }

    if (n0 >= 512) {
        // V tile: write transposed VT[b][h][hd][token], 4 tokens per b64 store.
        const int bb = m0 >> 11;
        const int tok0 = (m0 & 2047) + wr;
        #pragma unroll
        for (int i = 0; i < 2; ++i)
            #pragma unroll
            for (int j = 0; j < 4; ++j) {
                int vcol = n0 + wc + j * 16 + l16 - 512;
                int hh = vcol >> 5, d = vcol & 31;
                half4_t p;
                #pragma unroll
                for (int r = 0; r < 4; ++r) p[r] = (_Float16)acc[i][j][r];
                *reinterpret_cast<half4_t*>(
                    VTo + ((size_t)(bb * NHEADS + hh) * HDIM + d) * 2048
                        + tok0 + i * 16 + quad * 4) = p;
            }
    } else {
        #pragma unroll
        for (int i = 0; i < 2; ++i)
            #pragma unroll
            for (int r = 0; r < 4; ++r) {
                int row = m0 + wr + i * 16 + quad * 4 + r;
                #pragma unroll
                for (int j = 0; j < 4; ++j) {
                    int col = n0 + wc + j * 16 + l16;
                    float v = acc[i][j][r];
                    if (n0 < 256) v *= QS;  // pre-scale Q for exp2
                    Cv[(size_t)row * ldc + col] = (_Float16)v;
                }
            }
    }
}

// ---------------------------------------------------------------------------
// MFMA flash attention v12: block-shared LDS K/V staging (4x L2 traffic cut).
//  - 64 q/wave, key-split x2, 512 blocks, launch_bounds(256,2).
//  - K/V staged once per block per 64-key chunk via global_load_lds,
//    double-buffered; barrier-per-chunk (m97 structure). Stage issued BEFORE
//    compute so the barrier's vmcnt(0) drain is latency-covered.
//  - LDS fragment reads are XOR-unit-swizzled (linear LDS dest + pre-swizzled
//    per-lane GLOBAL source, m173 pattern) -> conflict-free ds_read_b128:
//      K  [64 tok][32 d]:  phys_unit = u ^ ((tok>>1)&3)
//      V^T[32 d][64 tok]:  phys_unit = u ^ (d&7)
//  - es transpose buffer: unit ^= (l16&3) on write AND read — fixes the
//    even-banks-only write conflict (3.1M SQ_LDS_BANK_CONFLICT).
//  - ones-MFMA denominator, exp2 on pre-scaled Q, pkrtz, setprio, XCD swizzle.
// ---------------------------------------------------------------------------

#define STAGE(bf_, ch_)                                                        \
    do {                                                                       \
        gload_lds16(ksrc + (size_t)(ch_) * 32768, &Ks[bf_][0][0] + wave * 512);\
        gload_lds16(vsrc + (ch_) * 64,            &Vs[bf_][0][0] + wave * 512);\
    } while (0)

#define COMPUTE(bf_)                                                           \
    do {                                                                       \
        half4_t ep[4][4];                                                      \
        _Pragma("unroll")                                                      \
        for (int kb = 0; kb < 4; ++kb) {                                       \
            half8_t kf = *reinterpret_cast<const half8_t*>(                    \
                &Ks[bf_][kb * 16 + l16][kswz * 8]);                            \
            _Pragma("unroll")                                                  \
            for (int g = 0; g < 4; ++g) {                                      \
                float4_t st = __builtin_amdgcn_mfma_f32_16x16x32_f16(          \
                    kf, qf[g], z, 0, 0, 0);                                    \
                auto lo = __builtin_amdgcn_cvt_pkrtz(fast_exp2(st[0]),         \
                                                     fast_exp2(st[1]));        \
                auto hi = __builtin_amdgcn_cvt_pkrtz(fast_exp2(st[2]),         \
                                                     fast_exp2(st[3]));        \
                ep[kb][g] = (half4_t){(_Float16)lo[0], (_Float16)lo[1],        \
                                      (_Float16)hi[0], (_Float16)hi[1]};       \
            }                                                                  \
        }                                                                      \
        _Pragma("unroll")                                                      \
        for (int s = 0; s < 2; ++s) {                                          \
            _Pragma("unroll")                                                  \
            for (int tt = 0; tt < 2; ++tt)                                     \
                _Pragma("unroll")                                              \
                for (int g = 0; g < 4; ++g)                                    \
                    *reinterpret_cast<half4_t*>(                               \
                        esw + (g * 16 + l16) * 40 +                            \
                        ((tt * 2 + (quad >> 1)) ^ esz) * 8 + (quad & 1) * 4) = \
                        ep[s * 2 + tt][g];                                     \
            half8_t vf0 = *reinterpret_cast<const half8_t*>(                   \
                &Vs[bf_][l16][((s * 4 + quad) ^ vsz) * 8]);                    \
            half8_t vf1 = *reinterpret_cast<const half8_t*>(                   \
                &Vs[bf_][16 + l16][((s * 4 + quad) ^ vsz) * 8]);               \
            _Pragma("unroll")                                                  \
            for (int g = 0; g < 4; ++g) {                                      \
                half8_t ef = *reinterpret_cast<const half8_t*>(                \
                    esw + (g * 16 + l16) * 40 + (quad ^ esz) * 8);             \
                num[g][0] = __builtin_amdgcn_mfma_f32_16x16x32_f16(            \
                    ef, vf0, num[g][0], 0, 0, 0);                              \
                num[g][1] = __builtin_amdgcn_mfma_f32_16x16x32_f16(            \
                    ef, vf1, num[g][1], 0, 0, 0);                              \
                dacc[g] = __builtin_amdgcn_mfma_f32_16x16x32_f16(              \
                    ef, onef, dacc[g], 0, 0, 0);                               \
            }                                                                  \
        }                                                                      \
    } while (0)

__global__ __launch_bounds__(256, 2) void attn_v12(const _Float16* __restrict__ qkh,
                                                   const _Float16* __restrict__ VT,
                                                   _Float16* __restrict__ NUM,
                                                   float* __restrict__ DEN) {
    __shared__ alignas(16) _Float16 Ks[2][64][32];   // 8KB, unit-swizzled
    __shared__ alignas(16) _Float16 Vs[2][32][64];   // 8KB, unit-swizzled
    __shared__ alignas(16) _Float16 es[4][64][40];   // 20KB, per-wave private
    // XCD swizzle (bijective, 512 % 8 == 0).
    const int bid = ((blockIdx.x & 7) << 6) | (blockIdx.x >> 3);
    const int kh = bid & 1;
    const int qb = (bid >> 1) & 7;
    const int bh = bid >> 4;
    const int b = bh >> 3, h = bh & 7;
    const int t = threadIdx.x, lane = t & 63, wave = t >> 6;
    const int l16 = lane & 15, quad = lane >> 4;
    const int bN = b * 2048;
    const int q0w = qb * 256 + wave * 64;
    const int kbeg = kh * 1024;

    // --- staging source addresses (pre-swizzled so linear LDS = swizzled) ---
    // K: wave w stages tokens w*16..+15; lane i -> (tok = w16+(i>>2),
    //    phys unit i&3, logical unit = (i&3) ^ ((i>>3)&3)).
    const int uk = (lane & 3) ^ ((lane >> 3) & 3);
    const _Float16* ksrc = qkh + (size_t)(bN + kbeg + wave * 16 + (lane >> 2)) * 512
                               + 256 + h * HDIM + uk * 8;
    // V: wave w stages d = w*8..+7; lane i -> (d = w8+(i>>3), phys unit i&7,
    //    logical unit = (i&7) ^ (i>>3)).
    const int uv = (lane & 7) ^ (lane >> 3);
    const _Float16* vsrc = VT + (size_t)bh * HDIM * 2048
                              + (size_t)(wave * 8 + (lane >> 3)) * 2048
                              + kbeg + uv * 8;
    // --- fragment-read swizzle constants ---
    const int kswz = quad ^ ((l16 >> 1) & 3);
    const int vsz = l16 & 7;
    const int esz = l16 & 3;

    // Q fragments (B-operand of S^T): pre-scaled by scale*log2e, in regs.
    half8_t qf[4];
    {
        const _Float16* qrow = qkh + (size_t)(bN + q0w + l16) * 512 + h * HDIM + quad * 8;
        #pragma unroll
        for (int g = 0; g < 4; ++g)
            qf[g] = *reinterpret_cast<const half8_t*>(qrow + (size_t)g * 16 * 512);
    }

    float4_t num[4][2];
    #pragma unroll
    for (int g = 0; g < 4; ++g)
        #pragma unroll
        for (int dt = 0; dt < 2; ++dt) num[g][dt] = (float4_t){0.f, 0.f, 0.f, 0.f};
    float4_t dacc[4];
    #pragma unroll
    for (int g = 0; g < 4; ++g) dacc[g] = (float4_t){0.f, 0.f, 0.f, 0.f};

    half8_t onef;
    #pragma unroll
    for (int j = 0; j < 8; ++j) onef[j] = (_Float16)1.0f;

    _Float16* esw = &es[wave][0][0];
    const float4_t z = {0.f, 0.f, 0.f, 0.f};

    // Prologue: stage chunk 0, then barrier (drains gload_lds vmcnt).
    STAGE(0, 0);
    __syncthreads();
    int bf = 0;
    for (int ch = 0; ch < 16; ++ch) {
        if (ch + 1 < 16) STAGE(bf ^ 1, ch + 1);  // issued early: latency covered
        __builtin_amdgcn_s_setprio(1);
        COMPUTE(bf);
        __builtin_amdgcn_s_setprio(0);
        __syncthreads();                          // drain stage + join waves
        bf ^= 1;
    }

    // Store partial numerator (fp16, unnormalized) and partial denom (fp32).
    _Float16* ob = NUM + (size_t)kh * 2097152 + (size_t)(bN + q0w) * DIM + h * HDIM;
    #pragma unroll
    for (int g = 0; g < 4; ++g)
        #pragma unroll
        for (int r = 0; r < 4; ++r) {
            size_t ro = (size_t)(g * 16 + quad * 4 + r) * DIM;
            ob[ro + l16]      = (_Float16)num[g][0][r];
            ob[ro + 16 + l16] = (_Float16)num[g][1][r];
        }
    if (l16 == 0) {
        #pragma unroll
        for (int g = 0; g < 4; ++g)
            #pragma unroll
            for (int r = 0; r < 4; ++r)
                DEN[kh * 65536 + bh * 2048 + q0w + g * 16 + quad * 4 + r] = dacc[g][r];
    }
}

// ---------------------------------------------------------------------------
// gemm_out: out = combine(NUM,DEN) @ WoT^T + bout, combine fused into the
// A-tile staging (BK=32 == HDIM: normalize NUM0+NUM1 by DEN0+DEN1, ds_write).
// ---------------------------------------------------------------------------
__global__ __launch_bounds__(256) void gemm_out(const _Float16* __restrict__ NUM,
                                                const float* __restrict__ DEN,
                                                const _Float16* __restrict__ BT,
                                                const float* __restrict__ bias,
                                                float* __restrict__ C) {
    constexpr int K = 256;
    __shared__ alignas(16) _Float16 As[64 * 32];
    __shared__ alignas(16) _Float16 Bs[128 * 32];
    const int t = threadIdx.x, lane = t & 63, wave = t >> 6;
    const int l16 = lane & 15, quad = lane >> 4;
    const int m0 = blockIdx.y * 64, n0 = blockIdx.x * 128;
    const int wr = (wave >> 1) * 32, wc = (wave & 1) * 64;
    float4_t acc[2][4];
    #pragma unroll
    for (int i = 0; i < 2; ++i)
        #pragma unroll
        for (int j = 0; j < 4; ++j) acc[i][j] = (float4_t){0.f, 0.f, 0.f, 0.f};

    const int srow = lane >> 2;
    const int scol = (lane & 3) * 8;
    const int ar = t >> 2;            // 0..63
    const int ac = (t & 3) * 8;       // 0,8,16,24
    const int row = m0 + ar;
    const int bb = row >> 11, tok = row & 2047;

    for (int k0 = 0; k0 < K; k0 += 32) {
        {   // A: normalize NUM partials -> fp16 -> LDS (same math as combine)
            const int h = k0 >> 5;
            const int di = (bb * 8 + h) * 2048 + tok;
            float den = DEN[di] + DEN[di + 65536] + 1e-6f;
            _Float16 rcp = (_Float16)(1.0f / den);
            size_t idx = (size_t)row * 256 + k0 + ac;
            half8_t nu0 = *reinterpret_cast<const half8_t*>(NUM + idx);
            half8_t nu1 = *reinterpret_cast<const half8_t*>(NUM + idx + 2097152);
            *reinterpret_cast<half8_t*>(As + ar * 32 + ac) = (nu0 + nu1) * rcp;
        }
        #pragma unroll
        for (int i = 0; i < 2; ++i) {
            int chunk = i * 4 + wave;
            int r = chunk * 16 + srow;
            gload_lds16(BT + (size_t)(n0 + r) * K + k0 + scol, Bs + chunk * 512);
        }
        __syncthreads();
        half8_t af[2], bf[4];
        #pragma unroll
        for (int i = 0; i < 2; ++i)
            af[i] = *reinterpret_cast<const half8_t*>(As + (wr + i * 16 + l16) * 32 + quad * 8);
        #pragma unroll
        for (int j = 0; j < 4; ++j)
            bf[j] = *reinterpret_cast<const half8_t*>(Bs + (wc + j * 16 + l16) * 32 + quad * 8);
        #pragma unroll
        for (int i = 0; i < 2; ++i)
            #pragma unroll
            for (int j = 0; j < 4; ++j)
                acc[i][j] = __builtin_amdgcn_mfma_f32_16x16x32_f16(af[i], bf[j], acc[i][j], 0, 0, 0);
        __syncthreads();
    }

    float bv[4];
    #pragma unroll
    for (int j = 0; j < 4; ++j) bv[j] = bias[n0 + wc + j * 16 + l16];
    #pragma unroll
    for (int i = 0; i < 2; ++i)
        #pragma unroll
        for (int r = 0; r < 4; ++r) {
            int orow = m0 + wr + i * 16 + quad * 4 + r;
            #pragma unroll
            for (int j = 0; j < 4; ++j) {
                int col = n0 + wc + j * 16 + l16;
                C[(size_t)orow * DIM + col] = acc[i][j][r] + bv[j];
            }
        }
}

extern "C" void kernel_launch(void* const* d_in, const int* in_sizes, int n_in,
                              void* d_out, int out_size, void* d_ws, size_t ws_size,
                              hipStream_t stream) {
    const float* x    = (const float*)d_in[0];
    const float* Wqkv = (const float*)d_in[1];
    const float* Wout = (const float*)d_in[2];
    const float* bout = (const float*)d_in[3];
    float* out = (float*)d_out;
    const int M = 8192;

    _Float16* xh    = (_Float16*)d_ws;                 // [8192,256]
    _Float16* WqT   = xh + (size_t)M * DIM;            // [768,256]
    _Float16* WoT   = WqT + 768 * 256;                 // [256,256]
    _Float16* qkh   = WoT + 256 * 256;                 // [8192,512]  (Q|K)
    _Float16* vt    = qkh + (size_t)M * 512;           // [4][8][32][2048] V^T
    _Float16* NUM   = vt + (size_t)32 * HDIM * 2048;   // [2][8192,256] partials
    float*    DEN   = (float*)(NUM + (size_t)2 * M * DIM);  // [2][65536]

    hipLaunchKernelGGL(prep, dim3(1280), dim3(256), 0, stream, x, Wqkv, Wout, xh, WqT, WoT);
    // qkv GEMM: Q (scaled by scale*log2e), K -> qkh (ldc 512); V -> vt transposed.
    hipLaunchKernelGGL(gemm_qkv, dim3(6, 128), dim3(256), 0, stream, xh, WqT, qkh, vt);
    // attention: 512 blocks (2/CU), 64 q/wave, key-split x2, LDS-staged K/V.
    hipLaunchKernelGGL(attn_v12, dim3(512), dim3(256), 0, stream, qkh, vt, NUM, DEN);
    // out = combine(NUM,DEN) @ Wout + bout, combine fused into A-staging.
    hipLaunchKernelGGL(gemm_out, dim3(2, 128), dim3(256), 0, stream,
                       NUM, DEN, WoT, bout, out);
}

// Round 10
// 123.356 us; speedup vs baseline: 1.0547x; 1.0547x over previous
//
#include <hip/hip_runtime.h>

#define DIM 256
#define NHEADS 8
#define HDIM 32

typedef _Float16 half8_t __attribute__((ext_vector_type(8)));
typedef _Float16 half4_t __attribute__((ext_vector_type(4)));
typedef float float4_t __attribute__((ext_vector_type(4)));

__device__ __forceinline__ float fast_exp2(float x) {
#if __has_builtin(__builtin_amdgcn_exp2f)
    return __builtin_amdgcn_exp2f(x);
#else
    return __expf(x * 0.6931471805599453f);
#endif
}

__device__ __forceinline__ void gload_lds16(const void* g, void* l) {
    __builtin_amdgcn_global_load_lds((const __attribute__((address_space(1))) void*)g,
                                     (__attribute__((address_space(3))) void*)l,
                                     16, 0, 0);
}

// ---------------------------------------------------------------------------
// prep: (a) x fp32 -> fp16 flat; (b) Wqkv [256,768] -> WqT [768,256] fp16;
//       (c) Wout [256,256] -> WoT [256,256] fp16 (transposed for B-frags).
// ---------------------------------------------------------------------------
__global__ __launch_bounds__(256) void prep(const float* __restrict__ x,
                                            const float* __restrict__ Wqkv,
                                            const float* __restrict__ Wout,
                                            _Float16* __restrict__ xh,
                                            _Float16* __restrict__ WqT,
                                            _Float16* __restrict__ WoT) {
    __shared__ float ts[32][33];
    const int bid = blockIdx.x, t = threadIdx.x;
    if (bid < 1024) {
        size_t idx = (size_t)bid * 2048 + (size_t)t * 8;
        float tmp[8];
        *reinterpret_cast<float4*>(tmp)     = *reinterpret_cast<const float4*>(x + idx);
        *reinterpret_cast<float4*>(tmp + 4) = *reinterpret_cast<const float4*>(x + idx + 4);
        half8_t h;
        #pragma unroll
        for (int j = 0; j < 8; ++j) h[j] = (_Float16)tmp[j];
        *reinterpret_cast<half8_t*>(xh + idx) = h;
    } else {
        const float* src; _Float16* dst; int K, N, kb, nb;
        if (bid < 1024 + 192) { int b2 = bid - 1024; src = Wqkv; dst = WqT; K = 256; N = 768; nb = b2 % 24; kb = b2 / 24; }
        else                  { int b3 = bid - 1216; src = Wout; dst = WoT; K = 256; N = 256; nb = b3 % 8;  kb = b3 / 8; }
        const int tx = t & 31, ty = t >> 5;
        #pragma unroll
        for (int i = 0; i < 4; ++i) {
            int k = kb * 32 + ty + i * 8;
            ts[ty + i * 8][tx] = src[(size_t)k * N + nb * 32 + tx];
        }
        __syncthreads();
        #pragma unroll
        for (int i = 0; i < 4; ++i) {
            int nl = ty + i * 8;
            dst[(size_t)(nb * 32 + nl) * K + kb * 32 + tx] = (_Float16)ts[tx][nl];
        }
    }
}

// ---------------------------------------------------------------------------
// fp16 MFMA GEMM (qkv): C[M,N] = A[M,K] @ BT[N,K]^T, LDS-staged.
// 64x128 tile, BK=32, 4 waves. Tiles with n0>=512 are V -> written TRANSPOSED
// to VT[b][h][hd][token]; Q columns (n0<256) pre-scaled by scale*log2(e).
// ---------------------------------------------------------------------------
__global__ __launch_bounds__(256) void gemm_qkv(const _Float16* __restrict__ A,
                                                const _Float16* __restrict__ BT,
                                                _Float16* __restrict__ Cv,
                                                _Float16* __restrict__ VTo) {
    constexpr int K = 256, ldc = 512;
    __shared__ alignas(16) _Float16 As[64 * 32];
    __shared__ alignas(16) _Float16 Bs[128 * 32];
    const int t = threadIdx.x, lane = t & 63, wave = t >> 6;
    const int l16 = lane & 15, quad = lane >> 4;
    const int m0 = blockIdx.y * 64, n0 = blockIdx.x * 128;
    const int wr = (wave >> 1) * 32, wc = (wave & 1) * 64;
    constexpr float QS = 0.17677669529663687f * 1.4426950408889634f;  // scale*log2e
    float4_t acc[2][4];
    #pragma unroll
    for (int i = 0; i < 2; ++i)
        #pragma unroll
        for (int j = 0; j < 4; ++j) acc[i][j] = (float4_t){0.f, 0.f, 0.f, 0.f};

    const int srow = lane >> 2;
    const int scol = (lane & 3) * 8;

    for (int k0 = 0; k0 < K; k0 += 32) {
        {
            int chunk = wave;                       // 4 chunks of 16 rows = 64
            int r = chunk * 16 + srow;
            gload_lds16(A + (size_t)(m0 + r) * K + k0 + scol, As + chunk * 512);
        }
        #pragma unroll
        for (int i = 0; i < 2; ++i) {
            int chunk = i * 4 + wave;
            int r = chunk * 16 + srow;
            gload_lds16(BT + (size_t)(n0 + r) * K + k0 + scol, Bs + chunk * 512);
        }
        __syncthreads();
        half8_t af[2], bf[4];
        #pragma unroll
        for (int i = 0; i < 2; ++i)
            af[i] = *reinterpret_cast<const half8_t*>(As + (wr + i * 16 + l16) * 32 + quad * 8);
        #pragma unroll
        for (int j = 0; j < 4; ++j)
            bf[j] = *reinterpret_cast<const half8_t*>(Bs + (wc + j * 16 + l16) * 32 + quad * 8);
        #pragma unroll
        for (int i = 0; i < 2; ++i)
            #pragma unroll
            for (int j = 0; j < 4; ++j)
                acc[i][j] = __builtin_amdgcn_mfma_f32_16x16x32_f16(af[i], bf[j], acc[i][j], 0, 0, 0);
        __syncthreads();
    }

    if (n0 >= 512) {
        // V tile: write transposed VT[b][h][hd][token], 4 tokens per b64 store.
        const int bb = m0 >> 11;
        const int tok0 = (m0 & 2047) + wr;
        #pragma unroll
        for (int i = 0; i < 2; ++i)
            #pragma unroll
            for (int j = 0; j < 4; ++j) {
                int vcol = n0 + wc + j * 16 + l16 - 512;
                int hh = vcol >> 5, d = vcol & 31;
                half4_t p;
                #pragma unroll
                for (int r = 0; r < 4; ++r) p[r] = (_Float16)acc[i][j][r];
                *reinterpret_cast<half4_t*>(
                    VTo + ((size_t)(bb * NHEADS + hh) * HDIM + d) * 2048
                        + tok0 + i * 16 + quad * 4) = p;
            }
    } else {
        #pragma unroll
        for (int i = 0; i < 2; ++i)
            #pragma unroll
            for (int r = 0; r < 4; ++r) {
                int row = m0 + wr + i * 16 + quad * 4 + r;
                #pragma unroll
                for (int j = 0; j < 4; ++j) {
                    int col = n0 + wc + j * 16 + l16;
                    float v = acc[i][j][r];
                    if (n0 < 256) v *= QS;  // pre-scale Q for exp2
                    Cv[(size_t)row * ldc + col] = (_Float16)v;
                }
            }
    }
}

// ---------------------------------------------------------------------------
// MFMA flash attention v13: v11 structure (proven 40us) + occupancy 2->3.
//  - 64 q/wave, key-split x2, 512 blocks, launch_bounds(256,3): 12 waves/CU
//    (v11's measured 70% stall time gets 1.5x more TLP cover).
//  - VGPR headroom for the 168 cap: STEP restructured per-s-chunk so only
//    8 ep half4s (16 VGPRs) are live instead of 16 (32 VGPRs). Same math,
//    same es write/read order within each s-chunk.
//  - K/V/Q loads inline-asm global_load_dwordx4 (un-sinkable, no hidden
//    vmcnt(0)); s_waitcnt vmcnt(8) counted pipeline; setprio on compute.
// ---------------------------------------------------------------------------

#define GLD(dst, addr) \
    asm volatile("global_load_dwordx4 %0, %1, off" : "=v"(dst) : "v"(addr))
#define WAITV(N) asm volatile("s_waitcnt vmcnt(" #N ")" ::: "memory")
#define SB0 __builtin_amdgcn_sched_barrier(0)

#define LOADASM(P, k0)                                            \
    do {                                                          \
        const _Float16* kp_ = kbase + (size_t)(k0) * 512;         \
        GLD(k##P[0], kp_);                                        \
        GLD(k##P[1], kp_ + (size_t)16 * 512);                     \
        GLD(k##P[2], kp_ + (size_t)32 * 512);                     \
        GLD(k##P[3], kp_ + (size_t)48 * 512);                     \
        const _Float16* vp_ = vbase + (k0);                       \
        GLD(v##P[0], vp_);                                        \
        GLD(v##P[1], vp_ + (size_t)16 * 2048);                    \
        GLD(v##P[2], vp_ + 32);                                   \
        GLD(v##P[3], vp_ + 32 + (size_t)16 * 2048);               \
    } while (0)

// Per-s-chunk: {2 kb of QK+exp (8 ep live)} -> es writes -> ef reads -> PV.
#define STEP(P)                                                                    \
    do {                                                                           \
        _Pragma("unroll")                                                          \
        for (int s = 0; s < 2; ++s) {                                              \
            half4_t ep[2][4];                                                      \
            _Pragma("unroll")                                                      \
            for (int tt = 0; tt < 2; ++tt) {                                       \
                _Pragma("unroll")                                                  \
                for (int g = 0; g < 4; ++g) {                                      \
                    float4_t st = __builtin_amdgcn_mfma_f32_16x16x32_f16(          \
                        k##P[s * 2 + tt], qf[g], z, 0, 0, 0);                      \
                    auto lo = __builtin_amdgcn_cvt_pkrtz(fast_exp2(st[0]),         \
                                                         fast_exp2(st[1]));        \
                    auto hi = __builtin_amdgcn_cvt_pkrtz(fast_exp2(st[2]),         \
                                                         fast_exp2(st[3]));        \
                    ep[tt][g] = (half4_t){(_Float16)lo[0], (_Float16)lo[1],        \
                                          (_Float16)hi[0], (_Float16)hi[1]};       \
                }                                                                  \
            }                                                                      \
            _Pragma("unroll")                                                      \
            for (int tt = 0; tt < 2; ++tt)                                         \
                _Pragma("unroll")                                                  \
                for (int g = 0; g < 4; ++g)                                        \
                    *reinterpret_cast<half4_t*>(                                   \
                        esw + (g * 16 + l16) * 40 + tt * 16 + quad * 4) =          \
                        ep[tt][g];                                                 \
            _Pragma("unroll")                                                      \
            for (int g = 0; g < 4; ++g) {                                          \
                half8_t ef = *reinterpret_cast<const half8_t*>(                    \
                    esw + (g * 16 + l16) * 40 + quad * 8);                         \
                num[g][0] = __builtin_amdgcn_mfma_f32_16x16x32_f16(                \
                    ef, v##P[s * 2], num[g][0], 0, 0, 0);                          \
                num[g][1] = __builtin_amdgcn_mfma_f32_16x16x32_f16(                \
                    ef, v##P[s * 2 + 1], num[g][1], 0, 0, 0);                      \
                dacc[g] = __builtin_amdgcn_mfma_f32_16x16x32_f16(                  \
                    ef, onef, dacc[g], 0, 0, 0);                                   \
            }                                                                      \
        }                                                                          \
    } while (0)

__global__ __launch_bounds__(256, 3) void attn_v13(const _Float16* __restrict__ qkh,
                                                   const _Float16* __restrict__ VT,
                                                   _Float16* __restrict__ NUM,
                                                   float* __restrict__ DEN) {
    __shared__ alignas(16) _Float16 es[4][64][40];
    // XCD swizzle (bijective, 512 % 8 == 0).
    const int bid = ((blockIdx.x & 7) << 6) | (blockIdx.x >> 3);
    const int kh = bid & 1;
    const int qb = (bid >> 1) & 7;
    const int bh = bid >> 4;
    const int b = bh >> 3, h = bh & 7;
    const int t = threadIdx.x, lane = t & 63, wave = t >> 6;
    const int l16 = lane & 15, quad = lane >> 4;
    const int bN = b * 2048;
    const int q0w = qb * 256 + wave * 64;
    const int kbeg = kh * 1024;

    const _Float16* kbase = qkh + (size_t)(bN + l16) * 512 + 256 + h * HDIM + quad * 8;
    const _Float16* vbase = VT + (size_t)bh * HDIM * 2048 + (size_t)l16 * 2048 + quad * 8;

    float4_t num[4][2];
    #pragma unroll
    for (int g = 0; g < 4; ++g)
        #pragma unroll
        for (int dt = 0; dt < 2; ++dt) num[g][dt] = (float4_t){0.f, 0.f, 0.f, 0.f};
    float4_t dacc[4];
    #pragma unroll
    for (int g = 0; g < 4; ++g) dacc[g] = (float4_t){0.f, 0.f, 0.f, 0.f};

    half8_t onef;
    #pragma unroll
    for (int j = 0; j < 8; ++j) onef[j] = (_Float16)1.0f;

    _Float16* esw = &es[wave][0][0];
    const float4_t z = {0.f, 0.f, 0.f, 0.f};

    // Q fragments via asm loads too: no compiler-tracked VMEM in the hot path.
    half8_t qf[4];
    {
        const _Float16* qrow = qkh + (size_t)(bN + q0w + l16) * 512 + h * HDIM + quad * 8;
        GLD(qf[0], qrow);
        GLD(qf[1], qrow + (size_t)16 * 512);
        GLD(qf[2], qrow + (size_t)32 * 512);
        GLD(qf[3], qrow + (size_t)48 * 512);
    }

    half8_t kA[4], vA[4], kB[4], vB[4];
    LOADASM(A, kbeg);                 // outstanding: 4 (qf) + 8 (A)
    for (int k0 = kbeg; k0 < kbeg + 1024; k0 += 128) {
        LOADASM(B, k0 + 64);          // + 8 (B)
        WAITV(8);                     // drain qf + A; B stays in flight
        SB0;
        __builtin_amdgcn_s_setprio(1);
        STEP(A);
        __builtin_amdgcn_s_setprio(0);
        if (k0 + 128 < kbeg + 1024) {
            LOADASM(A, k0 + 128);     // + 8 (A')
            WAITV(8);                 // drain B; A' stays in flight
        } else {
            WAITV(0);                 // tail: drain B
        }
        SB0;
        __builtin_amdgcn_s_setprio(1);
        STEP(B);
        __builtin_amdgcn_s_setprio(0);
    }

    // Store partial numerator (fp16, unnormalized) and partial denom (fp32).
    _Float16* ob = NUM + (size_t)kh * 2097152 + (size_t)(bN + q0w) * DIM + h * HDIM;
    #pragma unroll
    for (int g = 0; g < 4; ++g)
        #pragma unroll
        for (int r = 0; r < 4; ++r) {
            size_t ro = (size_t)(g * 16 + quad * 4 + r) * DIM;
            ob[ro + l16]      = (_Float16)num[g][0][r];
            ob[ro + 16 + l16] = (_Float16)num[g][1][r];
        }
    if (l16 == 0) {
        #pragma unroll
        for (int g = 0; g < 4; ++g)
            #pragma unroll
            for (int r = 0; r < 4; ++r)
                DEN[kh * 65536 + bh * 2048 + q0w + g * 16 + quad * 4 + r] = dacc[g][r];
    }
}

// ---------------------------------------------------------------------------
// gemm_out: out = combine(NUM,DEN) @ WoT^T + bout, combine fused into the
// A-tile staging (BK=32 == HDIM: normalize NUM0+NUM1 by DEN0+DEN1, ds_write).
// ---------------------------------------------------------------------------
__global__ __launch_bounds__(256) void gemm_out(const _Float16* __restrict__ NUM,
                                                const float* __restrict__ DEN,
                                                const _Float16* __restrict__ BT,
                                                const float* __restrict__ bias,
                                                float* __restrict__ C) {
    constexpr int K = 256;
    __shared__ alignas(16) _Float16 As[64 * 32];
    __shared__ alignas(16) _Float16 Bs[128 * 32];
    const int t = threadIdx.x, lane = t & 63, wave = t >> 6;
    const int l16 = lane & 15, quad = lane >> 4;
    const int m0 = blockIdx.y * 64, n0 = blockIdx.x * 128;
    const int wr = (wave >> 1) * 32, wc = (wave & 1) * 64;
    float4_t acc[2][4];
    #pragma unroll
    for (int i = 0; i < 2; ++i)
        #pragma unroll
        for (int j = 0; j < 4; ++j) acc[i][j] = (float4_t){0.f, 0.f, 0.f, 0.f};

    const int srow = lane >> 2;
    const int scol = (lane & 3) * 8;
    const int ar = t >> 2;            // 0..63
    const int ac = (t & 3) * 8;       // 0,8,16,24
    const int row = m0 + ar;
    const int bb = row >> 11, tok = row & 2047;

    for (int k0 = 0; k0 < K; k0 += 32) {
        {   // A: normalize NUM partials -> fp16 -> LDS (same math as combine)
            const int h = k0 >> 5;
            const int di = (bb * 8 + h) * 2048 + tok;
            float den = DEN[di] + DEN[di + 65536] + 1e-6f;
            _Float16 rcp = (_Float16)(1.0f / den);
            size_t idx = (size_t)row * 256 + k0 + ac;
            half8_t nu0 = *reinterpret_cast<const half8_t*>(NUM + idx);
            half8_t nu1 = *reinterpret_cast<const half8_t*>(NUM + idx + 2097152);
            *reinterpret_cast<half8_t*>(As + ar * 32 + ac) = (nu0 + nu1) * rcp;
        }
        #pragma unroll
        for (int i = 0; i < 2; ++i) {
            int chunk = i * 4 + wave;
            int r = chunk * 16 + srow;
            gload_lds16(BT + (size_t)(n0 + r) * K + k0 + scol, Bs + chunk * 512);
        }
        __syncthreads();
        half8_t af[2], bf[4];
        #pragma unroll
        for (int i = 0; i < 2; ++i)
            af[i] = *reinterpret_cast<const half8_t*>(As + (wr + i * 16 + l16) * 32 + quad * 8);
        #pragma unroll
        for (int j = 0; j < 4; ++j)
            bf[j] = *reinterpret_cast<const half8_t*>(Bs + (wc + j * 16 + l16) * 32 + quad * 8);
        #pragma unroll
        for (int i = 0; i < 2; ++i)
            #pragma unroll
            for (int j = 0; j < 4; ++j)
                acc[i][j] = __builtin_amdgcn_mfma_f32_16x16x32_f16(af[i], bf[j], acc[i][j], 0, 0, 0);
        __syncthreads();
    }

    float bv[4];
    #pragma unroll
    for (int j = 0; j < 4; ++j) bv[j] = bias[n0 + wc + j * 16 + l16];
    #pragma unroll
    for (int i = 0; i < 2; ++i)
        #pragma unroll
        for (int r = 0; r < 4; ++r) {
            int orow = m0 + wr + i * 16 + quad * 4 + r;
            #pragma unroll
            for (int j = 0; j < 4; ++j) {
                int col = n0 + wc + j * 16 + l16;
                C[(size_t)orow * DIM + col] = acc[i][j][r] + bv[j];
            }
        }
}

extern "C" void kernel_launch(void* const* d_in, const int* in_sizes, int n_in,
                              void* d_out, int out_size, void* d_ws, size_t ws_size,
                              hipStream_t stream) {
    const float* x    = (const float*)d_in[0];
    const float* Wqkv = (const float*)d_in[1];
    const float* Wout = (const float*)d_in[2];
    const float* bout = (const float*)d_in[3];
    float* out = (float*)d_out;
    const int M = 8192;

    _Float16* xh    = (_Float16*)d_ws;                 // [8192,256]
    _Float16* WqT   = xh + (size_t)M * DIM;            // [768,256]
    _Float16* WoT   = WqT + 768 * 256;                 // [256,256]
    _Float16* qkh   = WoT + 256 * 256;                 // [8192,512]  (Q|K)
    _Float16* vt    = qkh + (size_t)M * 512;           // [4][8][32][2048] V^T
    _Float16* NUM   = vt + (size_t)32 * HDIM * 2048;   // [2][8192,256] partials
    float*    DEN   = (float*)(NUM + (size_t)2 * M * DIM);  // [2][65536]

    hipLaunchKernelGGL(prep, dim3(1280), dim3(256), 0, stream, x, Wqkv, Wout, xh, WqT, WoT);
    // qkv GEMM: Q (scaled by scale*log2e), K -> qkh (ldc 512); V -> vt transposed.
    hipLaunchKernelGGL(gemm_qkv, dim3(6, 128), dim3(256), 0, stream, xh, WqT, qkh, vt);
    // attention: 512 blocks (3/CU now), 64 q/wave, key-split x2, asm prefetch.
    hipLaunchKernelGGL(attn_v13, dim3(512), dim3(256), 0, stream, qkh, vt, NUM, DEN);
    // out = combine(NUM,DEN) @ Wout + bout, combine fused into A-staging.
    hipLaunchKernelGGL(gemm_out, dim3(2, 128), dim3(256), 0, stream,
                       NUM, DEN, WoT, bout, out);
}

// Round 14
// 120.806 us; speedup vs baseline: 1.0769x; 1.0211x over previous
//
#include <hip/hip_runtime.h>

#define DIM 256
#define NHEADS 8
#define HDIM 32

typedef _Float16 half8_t __attribute__((ext_vector_type(8)));
typedef _Float16 half4_t __attribute__((ext_vector_type(4)));
typedef float float4_t __attribute__((ext_vector_type(4)));

__device__ __forceinline__ float fast_exp2(float x) {
#if __has_builtin(__builtin_amdgcn_exp2f)
    return __builtin_amdgcn_exp2f(x);
#else
    return __expf(x * 0.6931471805599453f);
#endif
}

__device__ __forceinline__ void gload_lds16(const void* g, void* l) {
    __builtin_amdgcn_global_load_lds((const __attribute__((address_space(1))) void*)g,
                                     (__attribute__((address_space(3))) void*)l,
                                     16, 0, 0);
}

// ---------------------------------------------------------------------------
// prep: (a) x fp32 -> fp16 flat; (b) Wqkv [256,768] -> WqT [768,256] fp16;
//       (c) Wout [256,256] -> WoT [256,256] fp16 (transposed for B-frags).
// ---------------------------------------------------------------------------
__global__ __launch_bounds__(256) void prep(const float* __restrict__ x,
                                            const float* __restrict__ Wqkv,
                                            const float* __restrict__ Wout,
                                            _Float16* __restrict__ xh,
                                            _Float16* __restrict__ WqT,
                                            _Float16* __restrict__ WoT) {
    __shared__ float ts[32][33];
    const int bid = blockIdx.x, t = threadIdx.x;
    if (bid < 1024) {
        size_t idx = (size_t)bid * 2048 + (size_t)t * 8;
        float tmp[8];
        *reinterpret_cast<float4*>(tmp)     = *reinterpret_cast<const float4*>(x + idx);
        *reinterpret_cast<float4*>(tmp + 4) = *reinterpret_cast<const float4*>(x + idx + 4);
        half8_t h;
        #pragma unroll
        for (int j = 0; j < 8; ++j) h[j] = (_Float16)tmp[j];
        *reinterpret_cast<half8_t*>(xh + idx) = h;
    } else {
        const float* src; _Float16* dst; int K, N, kb, nb;
        if (bid < 1024 + 192) { int b2 = bid - 1024; src = Wqkv; dst = WqT; K = 256; N = 768; nb = b2 % 24; kb = b2 / 24; }
        else                  { int b3 = bid - 1216; src = Wout; dst = WoT; K = 256; N = 256; nb = b3 % 8;  kb = b3 / 8; }
        const int tx = t & 31, ty = t >> 5;
        #pragma unroll
        for (int i = 0; i < 4; ++i) {
            int k = kb * 32 + ty + i * 8;
            ts[ty + i * 8][tx] = src[(size_t)k * N + nb * 32 + tx];
        }
        __syncthreads();
        #pragma unroll
        for (int i = 0; i < 4; ++i) {
            int nl = ty + i * 8;
            dst[(size_t)(nb * 32 + nl) * K + kb * 32 + tx] = (_Float16)ts[tx][nl];
        }
    }
}

// ---------------------------------------------------------------------------
// fp16 MFMA GEMM (qkv): C[M,N] = A[M,K] @ BT[N,K]^T, LDS-staged.
// 64x128 tile, BK=32, 4 waves. Tiles with n0>=512 are V -> written TRANSPOSED
// to VT[b][h][hd][token]; Q columns (n0<256) pre-scaled by scale*log2(e).
// ---------------------------------------------------------------------------
__global__ __launch_bounds__(256) void gemm_qkv(const _Float16* __restrict__ A,
                                                const _Float16* __restrict__ BT,
                                                _Float16* __restrict__ Cv,
                                                _Float16* __restrict__ VTo) {
    constexpr int K = 256, ldc = 512;
    __shared__ alignas(16) _Float16 As[64 * 32];
    __shared__ alignas(16) _Float16 Bs[128 * 32];
    const int t = threadIdx.x, lane = t & 63, wave = t >> 6;
    const int l16 = lane & 15, quad = lane >> 4;
    const int m0 = blockIdx.y * 64, n0 = blockIdx.x * 128;
    const int wr = (wave >> 1) * 32, wc = (wave & 1) * 64;
    constexpr float QS = 0.17677669529663687f * 1.4426950408889634f;  // scale*log2e
    float4_t acc[2][4];
    #pragma unroll
    for (int i = 0; i < 2; ++i)
        #pragma unroll
        for (int j = 0; j < 4; ++j) acc[i][j] = (float4_t){0.f, 0.f, 0.f, 0.f};

    const int srow = lane >> 2;
    const int scol = (lane & 3) * 8;

    for (int k0 = 0; k0 < K; k0 += 32) {
        {
            int chunk = wave;                       // 4 chunks of 16 rows = 64
            int r = chunk * 16 + srow;
            gload_lds16(A + (size_t)(m0 + r) * K + k0 + scol, As + chunk * 512);
        }
        #pragma unroll
        for (int i = 0; i < 2; ++i) {
            int chunk = i * 4 + wave;
            int r = chunk * 16 + srow;
            gload_lds16(BT + (size_t)(n0 + r) * K + k0 + scol, Bs + chunk * 512);
        }
        __syncthreads();
        half8_t af[2], bf[4];
        #pragma unroll
        for (int i = 0; i < 2; ++i)
            af[i] = *reinterpret_cast<const half8_t*>(As + (wr + i * 16 + l16) * 32 + quad * 8);
        #pragma unroll
        for (int j = 0; j < 4; ++j)
            bf[j] = *reinterpret_cast<const half8_t*>(Bs + (wc + j * 16 + l16) * 32 + quad * 8);
        #pragma unroll
        for (int i = 0; i < 2; ++i)
            #pragma unroll
            for (int j = 0; j < 4; ++j)
                acc[i][j] = __builtin_amdgcn_mfma_f32_16x16x32_f16(af[i], bf[j], acc[i][j], 0, 0, 0);
        __syncthreads();
    }

    if (n0 >= 512) {
        // V tile: write transposed VT[b][h][hd][token], 4 tokens per b64 store.
        const int bb = m0 >> 11;
        const int tok0 = (m0 & 2047) + wr;
        #pragma unroll
        for (int i = 0; i < 2; ++i)
            #pragma unroll
            for (int j = 0; j < 4; ++j) {
                int vcol = n0 + wc + j * 16 + l16 - 512;
                int hh = vcol >> 5, d = vcol & 31;
                half4_t p;
                #pragma unroll
                for (int r = 0; r < 4; ++r) p[r] = (_Float16)acc[i][j][r];
                *reinterpret_cast<half4_t*>(
                    VTo + ((size_t)(bb * NHEADS + hh) * HDIM + d) * 2048
                        + tok0 + i * 16 + quad * 4) = p;
            }
    } else {
        #pragma unroll
        for (int i = 0; i < 2; ++i)
            #pragma unroll
            for (int r = 0; r < 4; ++r) {
                int row = m0 + wr + i * 16 + quad * 4 + r;
                #pragma unroll
                for (int j = 0; j < 4; ++j) {
                    int col = n0 + wc + j * 16 + l16;
                    float v = acc[i][j][r];
                    if (n0 < 256) v *= QS;  // pre-scale Q for exp2
                    Cv[(size_t)row * ldc + col] = (_Float16)v;
                }
            }
    }
}

// ---------------------------------------------------------------------------
// MFMA flash attention v11 (+setprio): asm-load ping-pong, counted vmcnt.
//  - 64 q/wave, key-split x2, 512 blocks, launch_bounds(256,2).
//  - K/V/Q loads inline-asm global_load_dwordx4 (compiler cannot sink or
//    auto-drain); s_waitcnt vmcnt(8) keeps the next bank's 8 loads in
//    flight across the current STEP (counted-vmcnt pipeline, depth-1:
//    register pressure ~140 VGPR — no spills, so the vmcnt ledger is sound;
//    depth-2 (R11-R13) overflowed into scratch VMEM and corrupted it).
//  - s_setprio(1) around STEP: compute-phase waves win issue arbitration.
// ---------------------------------------------------------------------------

#define GLD(dst, addr) \
    asm volatile("global_load_dwordx4 %0, %1, off" : "=v"(dst) : "v"(addr))
#define WAITV(N) asm volatile("s_waitcnt vmcnt(" #N ")" ::: "memory")
#define SB0 __builtin_amdgcn_sched_barrier(0)

#define LOADASM(P, k0)                                            \
    do {                                                          \
        const _Float16* kp_ = kbase + (size_t)(k0) * 512;         \
        GLD(k##P[0], kp_);                                        \
        GLD(k##P[1], kp_ + (size_t)16 * 512);                     \
        GLD(k##P[2], kp_ + (size_t)32 * 512);                     \
        GLD(k##P[3], kp_ + (size_t)48 * 512);                     \
        const _Float16* vp_ = vbase + (k0);                       \
        GLD(v##P[0], vp_);                                        \
        GLD(v##P[1], vp_ + (size_t)16 * 2048);                    \
        GLD(v##P[2], vp_ + 32);                                   \
        GLD(v##P[3], vp_ + 32 + (size_t)16 * 2048);               \
    } while (0)

#define STEP(P)                                                                    \
    do {                                                                           \
        half4_t ep[4][4];                                                          \
        _Pragma("unroll")                                                          \
        for (int kb = 0; kb < 4; ++kb)                                             \
            _Pragma("unroll")                                                      \
            for (int g = 0; g < 4; ++g) {                                          \
                float4_t st = __builtin_amdgcn_mfma_f32_16x16x32_f16(              \
                    k##P[kb], qf[g], z, 0, 0, 0);                                  \
                auto lo = __builtin_amdgcn_cvt_pkrtz(fast_exp2(st[0]),             \
                                                     fast_exp2(st[1]));            \
                auto hi = __builtin_amdgcn_cvt_pkrtz(fast_exp2(st[2]),             \
                                                     fast_exp2(st[3]));            \
                ep[kb][g] = (half4_t){(_Float16)lo[0], (_Float16)lo[1],            \
                                      (_Float16)hi[0], (_Float16)hi[1]};           \
            }                                                                      \
        _Pragma("unroll")                                                          \
        for (int s = 0; s < 2; ++s) {                                              \
            _Pragma("unroll")                                                      \
            for (int tt = 0; tt < 2; ++tt)                                         \
                _Pragma("unroll")                                                  \
                for (int g = 0; g < 4; ++g)                                        \
                    *reinterpret_cast<half4_t*>(                                   \
                        esw + (g * 16 + l16) * 40 + tt * 16 + quad * 4) =          \
                        ep[s * 2 + tt][g];                                         \
            _Pragma("unroll")                                                      \
            for (int g = 0; g < 4; ++g) {                                          \
                half8_t ef = *reinterpret_cast<const half8_t*>(                    \
                    esw + (g * 16 + l16) * 40 + quad * 8);                         \
                num[g][0] = __builtin_amdgcn_mfma_f32_16x16x32_f16(                \
                    ef, v##P[s * 2], num[g][0], 0, 0, 0);                          \
                num[g][1] = __builtin_amdgcn_mfma_f32_16x16x32_f16(                \
                    ef, v##P[s * 2 + 1], num[g][1], 0, 0, 0);                      \
                dacc[g] = __builtin_amdgcn_mfma_f32_16x16x32_f16(                  \
                    ef, onef, dacc[g], 0, 0, 0);                                   \
            }                                                                      \
        }                                                                          \
    } while (0)

__global__ __launch_bounds__(256, 2) void attn_v11(const _Float16* __restrict__ qkh,
                                                   const _Float16* __restrict__ VT,
                                                   _Float16* __restrict__ NUM,
                                                   float* __restrict__ DEN) {
    __shared__ alignas(16) _Float16 es[4][64][40];
    // XCD swizzle (bijective, 512 % 8 == 0).
    const int bid = ((blockIdx.x & 7) << 6) | (blockIdx.x >> 3);
    const int kh = bid & 1;
    const int qb = (bid >> 1) & 7;
    const int bh = bid >> 4;
    const int b = bh >> 3, h = bh & 7;
    const int t = threadIdx.x, lane = t & 63, wave = t >> 6;
    const int l16 = lane & 15, quad = lane >> 4;
    const int bN = b * 2048;
    const int q0w = qb * 256 + wave * 64;
    const int kbeg = kh * 1024;

    const _Float16* kbase = qkh + (size_t)(bN + l16) * 512 + 256 + h * HDIM + quad * 8;
    const _Float16* vbase = VT + (size_t)bh * HDIM * 2048 + (size_t)l16 * 2048 + quad * 8;

    float4_t num[4][2];
    #pragma unroll
    for (int g = 0; g < 4; ++g)
        #pragma unroll
        for (int dt = 0; dt < 2; ++dt) num[g][dt] = (float4_t){0.f, 0.f, 0.f, 0.f};
    float4_t dacc[4];
    #pragma unroll
    for (int g = 0; g < 4; ++g) dacc[g] = (float4_t){0.f, 0.f, 0.f, 0.f};

    half8_t onef;
    #pragma unroll
    for (int j = 0; j < 8; ++j) onef[j] = (_Float16)1.0f;

    _Float16* esw = &es[wave][0][0];
    const float4_t z = {0.f, 0.f, 0.f, 0.f};

    // Q fragments via asm loads too: no compiler-tracked VMEM in the hot path.
    half8_t qf[4];
    {
        const _Float16* qrow = qkh + (size_t)(bN + q0w + l16) * 512 + h * HDIM + quad * 8;
        GLD(qf[0], qrow);
        GLD(qf[1], qrow + (size_t)16 * 512);
        GLD(qf[2], qrow + (size_t)32 * 512);
        GLD(qf[3], qrow + (size_t)48 * 512);
    }

    half8_t kA[4], vA[4], kB[4], vB[4];
    LOADASM(A, kbeg);                 // outstanding: 4 (qf) + 8 (A)
    for (int k0 = kbeg; k0 < kbeg + 1024; k0 += 128) {
        LOADASM(B, k0 + 64);          // + 8 (B)
        WAITV(8);                     // drain qf + A; B stays in flight
        SB0;
        __builtin_amdgcn_s_setprio(1);
        STEP(A);
        __builtin_amdgcn_s_setprio(0);
        if (k0 + 128 < kbeg + 1024) {
            LOADASM(A, k0 + 128);     // + 8 (A')
            WAITV(8);                 // drain B; A' stays in flight
        } else {
            WAITV(0);                 // tail: drain B
        }
        SB0;
        __builtin_amdgcn_s_setprio(1);
        STEP(B);
        __builtin_amdgcn_s_setprio(0);
    }

    // Store partial numerator (fp16, unnormalized) and partial denom (fp32).
    _Float16* ob = NUM + (size_t)kh * 2097152 + (size_t)(bN + q0w) * DIM + h * HDIM;
    #pragma unroll
    for (int g = 0; g < 4; ++g)
        #pragma unroll
        for (int r = 0; r < 4; ++r) {
            size_t ro = (size_t)(g * 16 + quad * 4 + r) * DIM;
            ob[ro + l16]      = (_Float16)num[g][0][r];
            ob[ro + 16 + l16] = (_Float16)num[g][1][r];
        }
    if (l16 == 0) {
        #pragma unroll
        for (int g = 0; g < 4; ++g)
            #pragma unroll
            for (int r = 0; r < 4; ++r)
                DEN[kh * 65536 + bh * 2048 + q0w + g * 16 + quad * 4 + r] = dacc[g][r];
    }
}

// ---------------------------------------------------------------------------
// gemm_out: out = combine(NUM,DEN) @ WoT^T + bout, with the combine fused
// into the A-tile staging (BK=32 == HDIM, so each A-tile is one head slice:
// normalize NUM0+NUM1 by DEN0+DEN1 in-register, ds_write fp16).
// ---------------------------------------------------------------------------
__global__ __launch_bounds__(256) void gemm_out(const _Float16* __restrict__ NUM,
                                                const float* __restrict__ DEN,
                                                const _Float16* __restrict__ BT,
                                                const float* __restrict__ bias,
                                                float* __restrict__ C) {
    constexpr int K = 256;
    __shared__ alignas(16) _Float16 As[64 * 32];
    __shared__ alignas(16) _Float16 Bs[128 * 32];
    const int t = threadIdx.x, lane = t & 63, wave = t >> 6;
    const int l16 = lane & 15, quad = lane >> 4;
    const int m0 = blockIdx.y * 64, n0 = blockIdx.x * 128;
    const int wr = (wave >> 1) * 32, wc = (wave & 1) * 64;
    float4_t acc[2][4];
    #pragma unroll
    for (int i = 0; i < 2; ++i)
        #pragma unroll
        for (int j = 0; j < 4; ++j) acc[i][j] = (float4_t){0.f, 0.f, 0.f, 0.f};

    const int srow = lane >> 2;
    const int scol = (lane & 3) * 8;
    // fused-combine A staging: thread -> (row, 8-col slice)
    const int ar = t >> 2;            // 0..63
    const int ac = (t & 3) * 8;       // 0,8,16,24
    const int row = m0 + ar;
    const int bb = row >> 11, tok = row & 2047;

    for (int k0 = 0; k0 < K; k0 += 32) {
        {   // A: normalize NUM partials -> fp16 -> LDS (same math as combine)
            const int h = k0 >> 5;
            const int di = (bb * 8 + h) * 2048 + tok;
            float den = DEN[di] + DEN[di + 65536] + 1e-6f;
            _Float16 rcp = (_Float16)(1.0f / den);
            size_t idx = (size_t)row * 256 + k0 + ac;
            half8_t nu0 = *reinterpret_cast<const half8_t*>(NUM + idx);
            half8_t nu1 = *reinterpret_cast<const half8_t*>(NUM + idx + 2097152);
            *reinterpret_cast<half8_t*>(As + ar * 32 + ac) = (nu0 + nu1) * rcp;
        }
        #pragma unroll
        for (int i = 0; i < 2; ++i) {
            int chunk = i * 4 + wave;
            int r = chunk * 16 + srow;
            gload_lds16(BT + (size_t)(n0 + r) * K + k0 + scol, Bs + chunk * 512);
        }
        __syncthreads();
        half8_t af[2], bf[4];
        #pragma unroll
        for (int i = 0; i < 2; ++i)
            af[i] = *reinterpret_cast<const half8_t*>(As + (wr + i * 16 + l16) * 32 + quad * 8);
        #pragma unroll
        for (int j = 0; j < 4; ++j)
            bf[j] = *reinterpret_cast<const half8_t*>(Bs + (wc + j * 16 + l16) * 32 + quad * 8);
        #pragma unroll
        for (int i = 0; i < 2; ++i)
            #pragma unroll
            for (int j = 0; j < 4; ++j)
                acc[i][j] = __builtin_amdgcn_mfma_f32_16x16x32_f16(af[i], bf[j], acc[i][j], 0, 0, 0);
        __syncthreads();
    }

    float bv[4];
    #pragma unroll
    for (int j = 0; j < 4; ++j) bv[j] = bias[n0 + wc + j * 16 + l16];
    #pragma unroll
    for (int i = 0; i < 2; ++i)
        #pragma unroll
        for (int r = 0; r < 4; ++r) {
            int orow = m0 + wr + i * 16 + quad * 4 + r;
            #pragma unroll
            for (int j = 0; j < 4; ++j) {
                int col = n0 + wc + j * 16 + l16;
                C[(size_t)orow * DIM + col] = acc[i][j][r] + bv[j];
            }
        }
}

extern "C" void kernel_launch(void* const* d_in, const int* in_sizes, int n_in,
                              void* d_out, int out_size, void* d_ws, size_t ws_size,
                              hipStream_t stream) {
    const float* x    = (const float*)d_in[0];
    const float* Wqkv = (const float*)d_in[1];
    const float* Wout = (const float*)d_in[2];
    const float* bout = (const float*)d_in[3];
    float* out = (float*)d_out;
    const int M = 8192;

    _Float16* xh    = (_Float16*)d_ws;                 // [8192,256]
    _Float16* WqT   = xh + (size_t)M * DIM;            // [768,256]
    _Float16* WoT   = WqT + 768 * 256;                 // [256,256]
    _Float16* qkh   = WoT + 256 * 256;                 // [8192,512]  (Q|K)
    _Float16* vt    = qkh + (size_t)M * 512;           // [4][8][32][2048] V^T
    _Float16* NUM   = vt + (size_t)32 * HDIM * 2048;   // [2][8192,256] partials
    float*    DEN   = (float*)(NUM + (size_t)2 * M * DIM);  // [2][65536]

    hipLaunchKernelGGL(prep, dim3(1280), dim3(256), 0, stream, x, Wqkv, Wout, xh, WqT, WoT);
    // qkv GEMM: Q (scaled by scale*log2e), K -> qkh (ldc 512); V -> vt transposed.
    hipLaunchKernelGGL(gemm_qkv, dim3(6, 128), dim3(256), 0, stream, xh, WqT, qkh, vt);
    // attention: 512 blocks (2/CU), 64 q/wave, key-split x2, asm prefetch.
    hipLaunchKernelGGL(attn_v11, dim3(512), dim3(256), 0, stream, qkh, vt, NUM, DEN);
    // out = combine(NUM,DEN) @ Wout + bout, combine fused into A-staging.
    hipLaunchKernelGGL(gemm_out, dim3(2, 128), dim3(256), 0, stream,
                       NUM, DEN, WoT, bout, out);
}